// Round 1
// baseline (616.898 us; speedup 1.0000x reference)
//
#include <hip/hip_runtime.h>

// GraphSAGE 2-layer, fp32, MI355X.
// Pipeline:
//   CSR build: hist(deg) -> scan(offs) -> fill(srcs sorted by dst)
//   mean1 = agg(x)/cnt                          [N,128]
//   h     = relu(mean1@W1l^T + x@W1r^T + b1)    [N,256]   (two-source GEMM)
//   Y2Z   = h @ [W2l | W2r]^T (+b2 on Z half)   [N,128]   (concat-weight GEMM)
//   out   = agg(Y2)/cnt + Z                     [N,64]    (64-dim gather: linearity trick)

#define IN_CH  128
#define HID_CH 256
#define OUT_CH 64

// ---------------- CSR build ----------------

__global__ void hist_kernel(const int* __restrict__ dst, int* __restrict__ deg, int E) {
    for (int e = blockIdx.x * blockDim.x + threadIdx.x; e < E; e += gridDim.x * blockDim.x)
        atomicAdd(&deg[dst[e]], 1);
}

__global__ void scan_block(const int* __restrict__ deg, int* __restrict__ offs,
                           int* __restrict__ bsum, int n) {
    __shared__ int s[512];
    int i = blockIdx.x * 512 + threadIdx.x;
    int v = (i < n) ? deg[i] : 0;
    s[threadIdx.x] = v;
    __syncthreads();
    #pragma unroll
    for (int d = 1; d < 512; d <<= 1) {
        int t = (threadIdx.x >= d) ? s[threadIdx.x - d] : 0;
        __syncthreads();
        s[threadIdx.x] += t;
        __syncthreads();
    }
    if (i < n) offs[i] = s[threadIdx.x] - v;        // exclusive within block
    if (threadIdx.x == 511) bsum[blockIdx.x] = s[511];
}

__global__ void scan_sums(int* __restrict__ bsum, int nb) {   // 1 block, 256 thr, nb<=256
    __shared__ int s[256];
    int v = (threadIdx.x < nb) ? bsum[threadIdx.x] : 0;
    s[threadIdx.x] = v;
    __syncthreads();
    #pragma unroll
    for (int d = 1; d < 256; d <<= 1) {
        int t = (threadIdx.x >= d) ? s[threadIdx.x - d] : 0;
        __syncthreads();
        s[threadIdx.x] += t;
        __syncthreads();
    }
    if (threadIdx.x < nb) bsum[threadIdx.x] = s[threadIdx.x] - v;  // exclusive
}

__global__ void scan_add(int* __restrict__ offs, const int* __restrict__ bsum, int n, int E) {
    int i = blockIdx.x * blockDim.x + threadIdx.x;
    if (i < n) offs[i] += bsum[i >> 9];
    if (i == 0) offs[n] = E;
}

__global__ void fill_csr(const int* __restrict__ src, const int* __restrict__ dst,
                         const int* __restrict__ offs, int* __restrict__ cur,
                         int* __restrict__ srcs, int E) {
    for (int e = blockIdx.x * blockDim.x + threadIdx.x; e < E; e += gridDim.x * blockDim.x) {
        int d = dst[e];
        int p = atomicAdd(&cur[d], 1);
        srcs[offs[d] + p] = src[e];
    }
}

// ---------------- aggregation (one wave per node) ----------------

__global__ __launch_bounds__(256) void agg_mean128(
    const float* __restrict__ X, const int* __restrict__ offs,
    const int* __restrict__ srcs, float* __restrict__ outm, int N) {
    int w = (blockIdx.x * 256 + threadIdx.x) >> 6;
    int lane = threadIdx.x & 63;
    if (w >= N) return;
    int s0 = offs[w], s1 = offs[w + 1];
    float ax = 0.f, ay = 0.f;
    for (int k = s0; k < s1; ++k) {
        int s = srcs[k];
        float2 v = *(const float2*)(X + (size_t)s * IN_CH + lane * 2);
        ax += v.x; ay += v.y;
    }
    int c = s1 - s0;
    float sc = 1.0f / (float)(c > 1 ? c : 1);
    float2 r; r.x = ax * sc; r.y = ay * sc;
    *(float2*)(outm + (size_t)w * IN_CH + lane * 2) = r;
}

// out[n][c] = mean_{s in nbrs(n)} Y2[s][c] + Z[n][c];  Y2Z layout [N][128], Y2=cols0..63, Z=64..127
__global__ __launch_bounds__(256) void agg_add_out(
    const float* __restrict__ Y2Z, const int* __restrict__ offs,
    const int* __restrict__ srcs, float* __restrict__ out, int N) {
    int w = (blockIdx.x * 256 + threadIdx.x) >> 6;
    int lane = threadIdx.x & 63;
    if (w >= N) return;
    int s0 = offs[w], s1 = offs[w + 1];
    float acc = 0.f;
    for (int k = s0; k < s1; ++k) {
        int s = srcs[k];
        acc += Y2Z[(size_t)s * 128 + lane];
    }
    int c = s1 - s0;
    float sc = 1.0f / (float)(c > 1 ? c : 1);
    out[(size_t)w * OUT_CH + lane] = acc * sc + Y2Z[(size_t)w * 128 + 64 + lane];
}

// ---------------- GEMMs (fp32 vector, 128x128 tile, 8x8 microtile) ----------------

// C[M,NT] = A1@W1^T + A2@W2^T + bias, optional relu.  A*:[M,KH], W*:[NT,KH]
template<bool RELU>
__global__ __launch_bounds__(256) void gemm_two_src(
    const float* __restrict__ A1, const float* __restrict__ A2,
    const float* __restrict__ W1, const float* __restrict__ W2,
    const float* __restrict__ bias, float* __restrict__ C,
    int M, int KH, int NT) {
    constexpr int BM = 128, BN = 128, BK = 32, TM = 8, TN = 8;
    __shared__ float As[BK][BM + 4];
    __shared__ float Bs[BK][BN + 4];
    const int tid = threadIdx.x;
    const int tx = tid & 15;
    const int ty = tid >> 4;
    const int row0 = blockIdx.x * BM;
    const int col0 = blockIdx.y * BN;
    const int lr = tid >> 3;            // 0..31
    const int lc = (tid & 7) * 4;       // 0,4,..,28
    float acc[TM][TN] = {};

    for (int phase = 0; phase < 2; ++phase) {
        const float* __restrict__ A = phase ? A2 : A1;
        const float* __restrict__ W = phase ? W2 : W1;
        for (int k0 = 0; k0 < KH; k0 += BK) {
            #pragma unroll
            for (int p = 0; p < BM / 32; ++p) {
                int r = lr + p * 32, gr = row0 + r;
                float4 v = make_float4(0.f, 0.f, 0.f, 0.f);
                if (gr < M) v = *(const float4*)(A + (size_t)gr * KH + k0 + lc);
                As[lc + 0][r] = v.x; As[lc + 1][r] = v.y;
                As[lc + 2][r] = v.z; As[lc + 3][r] = v.w;
            }
            #pragma unroll
            for (int p = 0; p < BN / 32; ++p) {
                int n = lr + p * 32, gn = col0 + n;
                float4 v = *(const float4*)(W + (size_t)gn * KH + k0 + lc);
                Bs[lc + 0][n] = v.x; Bs[lc + 1][n] = v.y;
                Bs[lc + 2][n] = v.z; Bs[lc + 3][n] = v.w;
            }
            __syncthreads();
            #pragma unroll
            for (int kk = 0; kk < BK; ++kk) {
                float a[TM], b[TN];
                #pragma unroll
                for (int i = 0; i < TM; ++i) a[i] = As[kk][ty * TM + i];
                #pragma unroll
                for (int j = 0; j < TN; ++j) b[j] = Bs[kk][tx * TN + j];
                #pragma unroll
                for (int i = 0; i < TM; ++i)
                    #pragma unroll
                    for (int j = 0; j < TN; ++j)
                        acc[i][j] += a[i] * b[j];
            }
            __syncthreads();
        }
    }
    #pragma unroll
    for (int i = 0; i < TM; ++i) {
        int gr = row0 + ty * TM + i;
        if (gr >= M) break;
        #pragma unroll
        for (int j = 0; j < TN; j += 4) {
            int gc = col0 + tx * TN + j;
            float4 v;
            v.x = acc[i][j + 0] + bias[gc + 0];
            v.y = acc[i][j + 1] + bias[gc + 1];
            v.z = acc[i][j + 2] + bias[gc + 2];
            v.w = acc[i][j + 3] + bias[gc + 3];
            if (RELU) {
                v.x = fmaxf(v.x, 0.f); v.y = fmaxf(v.y, 0.f);
                v.z = fmaxf(v.z, 0.f); v.w = fmaxf(v.w, 0.f);
            }
            *(float4*)(C + (size_t)gr * NT + gc) = v;
        }
    }
}

// C[M,128] = A @ [Wl|Wr]^T ; cols 0..63 <- Wl (no bias), cols 64..127 <- Wr (+bias)
__global__ __launch_bounds__(256) void gemm_concat_w(
    const float* __restrict__ A, const float* __restrict__ Wl,
    const float* __restrict__ Wr, const float* __restrict__ bias,
    float* __restrict__ C, int M, int K) {
    constexpr int BM = 128, BN = 128, BK = 32, TM = 8, TN = 8, HALF = 64;
    __shared__ float As[BK][BM + 4];
    __shared__ float Bs[BK][BN + 4];
    const int tid = threadIdx.x;
    const int tx = tid & 15;
    const int ty = tid >> 4;
    const int row0 = blockIdx.x * BM;
    const int lr = tid >> 3;
    const int lc = (tid & 7) * 4;
    float acc[TM][TN] = {};

    for (int k0 = 0; k0 < K; k0 += BK) {
        #pragma unroll
        for (int p = 0; p < BM / 32; ++p) {
            int r = lr + p * 32, gr = row0 + r;
            float4 v = make_float4(0.f, 0.f, 0.f, 0.f);
            if (gr < M) v = *(const float4*)(A + (size_t)gr * K + k0 + lc);
            As[lc + 0][r] = v.x; As[lc + 1][r] = v.y;
            As[lc + 2][r] = v.z; As[lc + 3][r] = v.w;
        }
        #pragma unroll
        for (int p = 0; p < BN / 32; ++p) {
            int n = lr + p * 32;
            const float* Wrow = (n < HALF) ? (Wl + (size_t)n * K) : (Wr + (size_t)(n - HALF) * K);
            float4 v = *(const float4*)(Wrow + k0 + lc);
            Bs[lc + 0][n] = v.x; Bs[lc + 1][n] = v.y;
            Bs[lc + 2][n] = v.z; Bs[lc + 3][n] = v.w;
        }
        __syncthreads();
        #pragma unroll
        for (int kk = 0; kk < BK; ++kk) {
            float a[TM], b[TN];
            #pragma unroll
            for (int i = 0; i < TM; ++i) a[i] = As[kk][ty * TM + i];
            #pragma unroll
            for (int j = 0; j < TN; ++j) b[j] = Bs[kk][tx * TN + j];
            #pragma unroll
            for (int i = 0; i < TM; ++i)
                #pragma unroll
                for (int j = 0; j < TN; ++j)
                    acc[i][j] += a[i] * b[j];
        }
        __syncthreads();
    }
    #pragma unroll
    for (int i = 0; i < TM; ++i) {
        int gr = row0 + ty * TM + i;
        if (gr >= M) break;
        #pragma unroll
        for (int j = 0; j < TN; j += 4) {
            int gc = tx * TN + j;    // 0..127; a float4 never straddles the 64 boundary
            float4 v;
            float b0 = (gc >= HALF) ? bias[gc - HALF + 0] : 0.f;
            float b1 = (gc >= HALF) ? bias[gc - HALF + 1] : 0.f;
            float b2 = (gc >= HALF) ? bias[gc - HALF + 2] : 0.f;
            float b3 = (gc >= HALF) ? bias[gc - HALF + 3] : 0.f;
            v.x = acc[i][j + 0] + b0;
            v.y = acc[i][j + 1] + b1;
            v.z = acc[i][j + 2] + b2;
            v.w = acc[i][j + 3] + b3;
            *(float4*)(C + (size_t)gr * 128 + gc) = v;
        }
    }
}

// ---------------- launch ----------------

extern "C" void kernel_launch(void* const* d_in, const int* in_sizes, int n_in,
                              void* d_out, int out_size, void* d_ws, size_t ws_size,
                              hipStream_t stream) {
    const float* x   = (const float*)d_in[0];
    const int*   ei  = (const int*)d_in[1];
    const float* W1l = (const float*)d_in[2];
    const float* b1  = (const float*)d_in[3];
    const float* W1r = (const float*)d_in[4];
    const float* W2l = (const float*)d_in[5];
    const float* b2  = (const float*)d_in[6];
    const float* W2r = (const float*)d_in[7];
    float* out = (float*)d_out;

    const int N = in_sizes[0] / IN_CH;      // 100000
    const int E = in_sizes[1] / 2;          // 640000
    const int* src = ei;
    const int* dst = ei + E;

    // workspace carve: h[N*256] | buf[N*128] (mean1, then Y2Z) | deg | offs | cur | bsum | srcs
    float* h   = (float*)d_ws;
    float* buf = h + (size_t)N * HID_CH;
    int* deg  = (int*)(buf + (size_t)N * 128);
    int* offs = deg + N;
    int* cur  = offs + (N + 8);
    int* bsum = cur + N;
    int* srcs = bsum + 512;

    hipMemsetAsync(deg, 0, sizeof(int) * N, stream);
    hipMemsetAsync(cur, 0, sizeof(int) * N, stream);

    hist_kernel<<<1024, 256, 0, stream>>>(dst, deg, E);
    int nb = (N + 511) / 512;               // 196 <= 256
    scan_block<<<nb, 512, 0, stream>>>(deg, offs, bsum, N);
    scan_sums<<<1, 256, 0, stream>>>(bsum, nb);
    scan_add<<<(N + 255) / 256, 256, 0, stream>>>(offs, bsum, N, E);
    fill_csr<<<1024, 256, 0, stream>>>(src, dst, offs, cur, srcs, E);

    // layer 1: aggregate-first (128-dim)
    agg_mean128<<<(N + 3) / 4, 256, 0, stream>>>(x, offs, srcs, buf, N);
    dim3 g1((N + 127) / 128, 2);
    gemm_two_src<true><<<g1, 256, 0, stream>>>(buf, x, W1l, W1r, b1, h, N, IN_CH, HID_CH);

    // layer 2: transform-first (linearity), then 64-dim aggregate
    dim3 g2((N + 127) / 128, 1);
    gemm_concat_w<<<g2, 256, 0, stream>>>(h, W2l, W2r, b2, buf, N, HID_CH);
    agg_add_out<<<(N + 3) / 4, 256, 0, stream>>>(buf, offs, srcs, out, N);
}

// Round 3
// 449.707 us; speedup vs baseline: 1.3718x; 1.3718x over previous
//
#include <hip/hip_runtime.h>

// GraphSAGE 2-layer, fp32 in/out, MI355X.
//   CSR build -> mean1 = agg(x)/cnt -> h = relu([mean1|x]@[W1l|W1r]^T + b1)   (split-bf16 MFMA)
//   Y2Z = h@[W2l;W2r]^T (+b2 on Z half)  (split-bf16 MFMA) -> out = agg(Y2)/cnt + Z
// Split-bf16: v = hi + lo (both bf16); A@B ~= Ahi@Bhi + Ahi@Blo + Alo@Bhi (fp32 acc, ~2^-16 rel err)

#define IN_CH  128
#define HID_CH 256
#define OUT_CH 64

typedef __bf16 bf16x8 __attribute__((ext_vector_type(8)));
typedef __bf16 bf16x4 __attribute__((ext_vector_type(4)));
typedef float  f32x4  __attribute__((ext_vector_type(4)));

// ---------------- CSR build ----------------

__global__ void hist_kernel(const int* __restrict__ dst, int* __restrict__ deg, int E) {
    for (int e = blockIdx.x * blockDim.x + threadIdx.x; e < E; e += gridDim.x * blockDim.x)
        atomicAdd(&deg[dst[e]], 1);
}

__global__ void scan_block(const int* __restrict__ deg, int* __restrict__ offs,
                           int* __restrict__ bsum, int n) {
    __shared__ int s[512];
    int i = blockIdx.x * 512 + threadIdx.x;
    int v = (i < n) ? deg[i] : 0;
    s[threadIdx.x] = v;
    __syncthreads();
    #pragma unroll
    for (int d = 1; d < 512; d <<= 1) {
        int t = (threadIdx.x >= d) ? s[threadIdx.x - d] : 0;
        __syncthreads();
        s[threadIdx.x] += t;
        __syncthreads();
    }
    if (i < n) offs[i] = s[threadIdx.x] - v;
    if (threadIdx.x == 511) bsum[blockIdx.x] = s[511];
}

__global__ void scan_sums(int* __restrict__ bsum, int nb) {
    __shared__ int s[256];
    int v = (threadIdx.x < nb) ? bsum[threadIdx.x] : 0;
    s[threadIdx.x] = v;
    __syncthreads();
    #pragma unroll
    for (int d = 1; d < 256; d <<= 1) {
        int t = (threadIdx.x >= d) ? s[threadIdx.x - d] : 0;
        __syncthreads();
        s[threadIdx.x] += t;
        __syncthreads();
    }
    if (threadIdx.x < nb) bsum[threadIdx.x] = s[threadIdx.x] - v;
}

__global__ void scan_add(int* __restrict__ offs, const int* __restrict__ bsum, int n, int E) {
    int i = blockIdx.x * blockDim.x + threadIdx.x;
    if (i < n) offs[i] += bsum[i >> 9];
    if (i == 0) offs[n] = E;
}

__global__ void fill_csr(const int* __restrict__ src, const int* __restrict__ dst,
                         const int* __restrict__ offs, int* __restrict__ cur,
                         int* __restrict__ srcs, int E) {
    for (int e = blockIdx.x * blockDim.x + threadIdx.x; e < E; e += gridDim.x * blockDim.x) {
        int d = dst[e];
        int p = atomicAdd(&cur[d], 1);
        srcs[offs[d] + p] = src[e];
    }
}

// ---------------- weight split (fp32 -> bf16 hi/lo), once per launch ----------------

__global__ void convert_weights(const float* __restrict__ W1l, const float* __restrict__ W1r,
                                const float* __restrict__ W2l, const float* __restrict__ W2r,
                                const float* __restrict__ b2,
                                __bf16* __restrict__ W1h, __bf16* __restrict__ W1lo,
                                __bf16* __restrict__ W2h, __bf16* __restrict__ W2lo,
                                float* __restrict__ bias2) {
    int i = blockIdx.x * 256 + threadIdx.x;
    if (i < 256 * 256) {                 // W1cat [256][256]: k<128 from W1l, else W1r
        int n = i >> 8, k = i & 255;
        float v = (k < 128) ? W1l[n * 128 + k] : W1r[n * 128 + (k - 128)];
        __bf16 h = (__bf16)v;
        W1h[i] = h; W1lo[i] = (__bf16)(v - (float)h);
    }
    if (i < 128 * 256) {                 // W2cat [128][256]: n<64 from W2l (Y2), else W2r (Z)
        int n = i >> 8, k = i & 255;
        float v = (n < 64) ? W2l[n * 256 + k] : W2r[(n - 64) * 256 + k];
        __bf16 h = (__bf16)v;
        W2h[i] = h; W2lo[i] = (__bf16)(v - (float)h);
    }
    if (i < 128) bias2[i] = (i < 64) ? 0.f : b2[i - 64];
}

// ---------------- aggregation (one wave per node) ----------------

__global__ __launch_bounds__(256) void agg_mean128(
    const float* __restrict__ X, const int* __restrict__ offs,
    const int* __restrict__ srcs, float* __restrict__ outm, int N) {
    int w = (blockIdx.x * 256 + threadIdx.x) >> 6;
    int lane = threadIdx.x & 63;
    if (w >= N) return;
    int s0 = offs[w], s1 = offs[w + 1];
    float ax = 0.f, ay = 0.f;
    for (int k = s0; k < s1; ++k) {
        int s = srcs[k];
        float2 v = *(const float2*)(X + (size_t)s * IN_CH + lane * 2);
        ax += v.x; ay += v.y;
    }
    int c = s1 - s0;
    float sc = 1.0f / (float)(c > 1 ? c : 1);
    float2 r; r.x = ax * sc; r.y = ay * sc;
    *(float2*)(outm + (size_t)w * IN_CH + lane * 2) = r;
}

__global__ __launch_bounds__(256) void agg_add_out(
    const float* __restrict__ Y2Z, const int* __restrict__ offs,
    const int* __restrict__ srcs, float* __restrict__ out, int N) {
    int w = (blockIdx.x * 256 + threadIdx.x) >> 6;
    int lane = threadIdx.x & 63;
    if (w >= N) return;
    int s0 = offs[w], s1 = offs[w + 1];
    float acc = 0.f;
    for (int k = s0; k < s1; ++k) {
        int s = srcs[k];
        acc += Y2Z[(size_t)s * 128 + lane];
    }
    int c = s1 - s0;
    float sc = 1.0f / (float)(c > 1 ? c : 1);
    out[(size_t)w * OUT_CH + lane] = acc * sc + Y2Z[(size_t)w * 128 + 64 + lane];
}

// ---------------- split-bf16 MFMA GEMM ----------------
// C[M][NT] = (A' @ Wcat^T) + bias, A'[r][k] = (k<Ksplit ? A1[r][k] : A2[r][k-Ksplit])
// Wcat given pre-split as Whi/Wlo [NT][K] bf16. Tile 128x128, BK=32, 4 waves (2x2), 64x64/wave.
// LDS rows of 32 bf16 (64B), XOR swizzle: byte_off ^= ((row>>1)&3)<<4.
//   Bank-group (addr bits 4..6) = {r&1, lg ^ ((r>>1)&3)} -> all 8 groups hit across 16
//   consecutive rows => 2-way (free) ds_read_b128. (r&3 variant left bit6/bit4 correlated: 4-way.)

template<bool RELU>
__global__ __launch_bounds__(256) void gemm_split(
    const float* __restrict__ A1, int lda1,
    const float* __restrict__ A2, int lda2, int Ksplit,
    const __bf16* __restrict__ Whi, const __bf16* __restrict__ Wlo,
    const float* __restrict__ bias, float* __restrict__ C,
    int M, int K, int NT) {
    __shared__ __bf16 Ah[128 * 32], Al[128 * 32], Bh[128 * 32], Bl[128 * 32];
    const int tid = threadIdx.x;
    const int lane = tid & 63;
    const int wid = tid >> 6;
    const int wm = wid >> 1, wn = wid & 1;
    const int l15 = lane & 15, lg = lane >> 4;
    const long row0 = (long)blockIdx.x * 128;
    const int col0 = blockIdx.y * 128;

    const int ar  = tid >> 3;            // A-stage row 0..31 (+p*32)
    const int acx = (tid & 7) * 4;       // A-stage float col
    const int wrr = tid >> 2;            // W-stage row 0..63 (+p*64)
    const int wcx = (tid & 3) * 8;       // W-stage bf16 col

    f32x4 acc[4][4] = {};

    for (int k0 = 0; k0 < K; k0 += 32) {
        const float* Asrc; int lda, kk0;
        if (k0 < Ksplit) { Asrc = A1; lda = lda1; kk0 = k0; }
        else             { Asrc = A2; lda = lda2; kk0 = k0 - Ksplit; }

        // stage A: 128x32 fp32 -> hi/lo bf16 in LDS (swizzled)
        #pragma unroll
        for (int p = 0; p < 4; ++p) {
            int r = ar + p * 32;
            long gr = row0 + r;
            float4 v = make_float4(0.f, 0.f, 0.f, 0.f);
            if (gr < M) v = *(const float4*)(Asrc + gr * (long)lda + kk0 + acx);
            __bf16 h0 = (__bf16)v.x, h1 = (__bf16)v.y, h2 = (__bf16)v.z, h3 = (__bf16)v.w;
            bf16x4 hv, lv;
            hv[0] = h0; hv[1] = h1; hv[2] = h2; hv[3] = h3;
            lv[0] = (__bf16)(v.x - (float)h0); lv[1] = (__bf16)(v.y - (float)h1);
            lv[2] = (__bf16)(v.z - (float)h2); lv[3] = (__bf16)(v.w - (float)h3);
            int off = (r * 64 + acx * 2) ^ (((r >> 1) & 3) << 4);
            *(bf16x4*)((char*)Ah + off) = hv;
            *(bf16x4*)((char*)Al + off) = lv;
        }
        // stage W: 128x32 bf16 hi/lo (pre-split in global) -> LDS (swizzled)
        #pragma unroll
        for (int p = 0; p < 2; ++p) {
            int n = wrr + p * 64;
            long wrow = (long)(col0 + n) * K + k0 + wcx;
            bf16x8 hv = *(const bf16x8*)(Whi + wrow);
            bf16x8 lv = *(const bf16x8*)(Wlo + wrow);
            int off = (n * 64 + wcx * 2) ^ (((n >> 1) & 3) << 4);
            *(bf16x8*)((char*)Bh + off) = hv;
            *(bf16x8*)((char*)Bl + off) = lv;
        }
        __syncthreads();

        bf16x8 ah[4], al[4], bh[4], bl[4];
        #pragma unroll
        for (int m = 0; m < 4; ++m) {
            int r = wm * 64 + m * 16 + l15;
            int off = (r * 64 + lg * 16) ^ (((r >> 1) & 3) << 4);
            ah[m] = *(const bf16x8*)((char*)Ah + off);
            al[m] = *(const bf16x8*)((char*)Al + off);
        }
        #pragma unroll
        for (int n = 0; n < 4; ++n) {
            int r = wn * 64 + n * 16 + l15;
            int off = (r * 64 + lg * 16) ^ (((r >> 1) & 3) << 4);
            bh[n] = *(const bf16x8*)((char*)Bh + off);
            bl[n] = *(const bf16x8*)((char*)Bl + off);
        }
        #pragma unroll
        for (int m = 0; m < 4; ++m)
            #pragma unroll
            for (int n = 0; n < 4; ++n) {
                acc[m][n] = __builtin_amdgcn_mfma_f32_16x16x32_bf16(ah[m], bh[n], acc[m][n], 0, 0, 0);
                acc[m][n] = __builtin_amdgcn_mfma_f32_16x16x32_bf16(ah[m], bl[n], acc[m][n], 0, 0, 0);
                acc[m][n] = __builtin_amdgcn_mfma_f32_16x16x32_bf16(al[m], bh[n], acc[m][n], 0, 0, 0);
            }
        __syncthreads();
    }

    // epilogue: C/D layout col=lane&15, row=(lane>>4)*4+reg  [m89]
    float bvals[4];
    #pragma unroll
    for (int n = 0; n < 4; ++n) bvals[n] = bias[col0 + wn * 64 + n * 16 + l15];
    #pragma unroll
    for (int m = 0; m < 4; ++m) {
        long gr0 = row0 + wm * 64 + m * 16 + lg * 4;
        #pragma unroll
        for (int rr = 0; rr < 4; ++rr) {
            long gr = gr0 + rr;
            if (gr < M) {
                #pragma unroll
                for (int n = 0; n < 4; ++n) {
                    int gc = col0 + wn * 64 + n * 16 + l15;
                    float v = acc[m][n][rr] + bvals[n];
                    if (RELU) v = fmaxf(v, 0.f);
                    C[gr * NT + gc] = v;
                }
            }
        }
    }
}

// ---------------- launch ----------------

extern "C" void kernel_launch(void* const* d_in, const int* in_sizes, int n_in,
                              void* d_out, int out_size, void* d_ws, size_t ws_size,
                              hipStream_t stream) {
    const float* x   = (const float*)d_in[0];
    const int*   ei  = (const int*)d_in[1];
    const float* W1l = (const float*)d_in[2];
    const float* b1  = (const float*)d_in[3];
    const float* W1r = (const float*)d_in[4];
    const float* W2l = (const float*)d_in[5];
    const float* b2  = (const float*)d_in[6];
    const float* W2r = (const float*)d_in[7];
    float* out = (float*)d_out;

    const int N = in_sizes[0] / IN_CH;      // 100000
    const int E = in_sizes[1] / 2;          // 640000
    const int* src = ei;
    const int* dst = ei + E;

    // ws carve: h[N*256] | buf[N*128] | CSR ints | bf16 weight splits | bias2
    float* h   = (float*)d_ws;
    float* buf = h + (size_t)N * HID_CH;
    int* deg  = (int*)(buf + (size_t)N * 128);
    int* offs = deg + N;
    int* cur  = offs + (N + 8);
    int* bsum = cur + N;
    int* srcs = bsum + 512;
    uintptr_t pp = (uintptr_t)(srcs + E);
    pp = (pp + 15) & ~(uintptr_t)15;
    __bf16* W1h  = (__bf16*)pp;             // [256][256]
    __bf16* W1lo = W1h + 256 * 256;
    __bf16* W2h  = W1lo + 256 * 256;        // [128][256]
    __bf16* W2lo = W2h + 128 * 256;
    float* bias2 = (float*)(W2lo + 128 * 256);

    hipMemsetAsync(deg, 0, sizeof(int) * N, stream);
    hipMemsetAsync(cur, 0, sizeof(int) * N, stream);

    convert_weights<<<256, 256, 0, stream>>>(W1l, W1r, W2l, W2r, b2,
                                             W1h, W1lo, W2h, W2lo, bias2);

    hist_kernel<<<1024, 256, 0, stream>>>(dst, deg, E);
    int nb = (N + 511) / 512;
    scan_block<<<nb, 512, 0, stream>>>(deg, offs, bsum, N);
    scan_sums<<<1, 256, 0, stream>>>(bsum, nb);
    scan_add<<<(N + 255) / 256, 256, 0, stream>>>(offs, bsum, N, E);
    fill_csr<<<1024, 256, 0, stream>>>(src, dst, offs, cur, srcs, E);

    // layer 1: aggregate-first, then h = relu([mean1|x] @ [W1l|W1r]^T + b1)
    agg_mean128<<<(N + 3) / 4, 256, 0, stream>>>(x, offs, srcs, buf, N);
    dim3 g1((N + 127) / 128, 2);
    gemm_split<true><<<g1, 256, 0, stream>>>(buf, IN_CH, x, IN_CH, IN_CH,
                                             W1h, W1lo, b1, h, N, 2 * IN_CH, HID_CH);

    // layer 2: transform-first Y2Z = h @ [W2l;W2r]^T (+bias2 masked), then 64-dim aggregate
    dim3 g2((N + 127) / 128, 1);
    gemm_split<false><<<g2, 256, 0, stream>>>(nullptr, 0, h, HID_CH, 0,
                                              W2h, W2lo, bias2, buf, N, HID_CH, 2 * OUT_CH);
    agg_add_out<<<(N + 3) / 4, 256, 0, stream>>>(buf, offs, srcs, out, N);
}

// Round 4
// 376.648 us; speedup vs baseline: 1.6379x; 1.1940x over previous
//
#include <hip/hip_runtime.h>

// GraphSAGE 2-layer, fp32 in/out, MI355X.
//   CSR build -> mean1 = agg(x)/cnt -> h = relu([mean1|x]@[W1l|W1r]^T + b1)   (split-bf16 MFMA)
//   Y2Z = h@[W2l;W2r]^T (+b2 on Z half)  (split-bf16 MFMA) -> out = agg(Y2)/cnt + Z
// Split-bf16: v = hi + lo (both bf16); A@B ~= Ahi@Bhi + Ahi@Blo + Alo@Bhi (fp32 acc, ~2^-16 rel err)
// R3: aggregation kernels rebuilt for MLP — multi-node waves + 4x edge unroll
//     (R2 profile: agg latency-bound, 1 dependent gather chain/wave, all pipes <30%).

#define IN_CH  128
#define HID_CH 256
#define OUT_CH 64

typedef __bf16 bf16x8 __attribute__((ext_vector_type(8)));
typedef __bf16 bf16x4 __attribute__((ext_vector_type(4)));
typedef float  f32x4  __attribute__((ext_vector_type(4)));

// ---------------- CSR build ----------------

__global__ void hist_kernel(const int* __restrict__ dst, int* __restrict__ deg, int E) {
    for (int e = blockIdx.x * blockDim.x + threadIdx.x; e < E; e += gridDim.x * blockDim.x)
        atomicAdd(&deg[dst[e]], 1);
}

__global__ void scan_block(const int* __restrict__ deg, int* __restrict__ offs,
                           int* __restrict__ bsum, int n) {
    __shared__ int s[512];
    int i = blockIdx.x * 512 + threadIdx.x;
    int v = (i < n) ? deg[i] : 0;
    s[threadIdx.x] = v;
    __syncthreads();
    #pragma unroll
    for (int d = 1; d < 512; d <<= 1) {
        int t = (threadIdx.x >= d) ? s[threadIdx.x - d] : 0;
        __syncthreads();
        s[threadIdx.x] += t;
        __syncthreads();
    }
    if (i < n) offs[i] = s[threadIdx.x] - v;
    if (threadIdx.x == 511) bsum[blockIdx.x] = s[511];
}

__global__ void scan_sums(int* __restrict__ bsum, int nb) {
    __shared__ int s[256];
    int v = (threadIdx.x < nb) ? bsum[threadIdx.x] : 0;
    s[threadIdx.x] = v;
    __syncthreads();
    #pragma unroll
    for (int d = 1; d < 256; d <<= 1) {
        int t = (threadIdx.x >= d) ? s[threadIdx.x - d] : 0;
        __syncthreads();
        s[threadIdx.x] += t;
        __syncthreads();
    }
    if (threadIdx.x < nb) bsum[threadIdx.x] = s[threadIdx.x] - v;
}

__global__ void scan_add(int* __restrict__ offs, const int* __restrict__ bsum, int n, int E) {
    int i = blockIdx.x * blockDim.x + threadIdx.x;
    if (i < n) offs[i] += bsum[i >> 9];
    if (i == 0) offs[n] = E;
}

__global__ void fill_csr(const int* __restrict__ src, const int* __restrict__ dst,
                         const int* __restrict__ offs, int* __restrict__ cur,
                         int* __restrict__ srcs, int E) {
    for (int e = blockIdx.x * blockDim.x + threadIdx.x; e < E; e += gridDim.x * blockDim.x) {
        int d = dst[e];
        int p = atomicAdd(&cur[d], 1);
        srcs[offs[d] + p] = src[e];
    }
}

// ---------------- weight split (fp32 -> bf16 hi/lo), once per launch ----------------

__global__ void convert_weights(const float* __restrict__ W1l, const float* __restrict__ W1r,
                                const float* __restrict__ W2l, const float* __restrict__ W2r,
                                const float* __restrict__ b2,
                                __bf16* __restrict__ W1h, __bf16* __restrict__ W1lo,
                                __bf16* __restrict__ W2h, __bf16* __restrict__ W2lo,
                                float* __restrict__ bias2) {
    int i = blockIdx.x * 256 + threadIdx.x;
    if (i < 256 * 256) {                 // W1cat [256][256]: k<128 from W1l, else W1r
        int n = i >> 8, k = i & 255;
        float v = (k < 128) ? W1l[n * 128 + k] : W1r[n * 128 + (k - 128)];
        __bf16 h = (__bf16)v;
        W1h[i] = h; W1lo[i] = (__bf16)(v - (float)h);
    }
    if (i < 128 * 256) {                 // W2cat [128][256]: n<64 from W2l (Y2), else W2r (Z)
        int n = i >> 8, k = i & 255;
        float v = (n < 64) ? W2l[n * 256 + k] : W2r[(n - 64) * 256 + k];
        __bf16 h = (__bf16)v;
        W2h[i] = h; W2lo[i] = (__bf16)(v - (float)h);
    }
    if (i < 128) bias2[i] = (i < 64) ? 0.f : b2[i - 64];
}

// ---------------- aggregation (multi-node waves, 4x unrolled gathers) ----------------

// 2 nodes per wave: 32 lanes x float4 = 512B = one 128-ch fp32 row.
__global__ __launch_bounds__(256) void agg_mean128(
    const float* __restrict__ X, const int* __restrict__ offs,
    const int* __restrict__ srcs, float* __restrict__ outm, int N) {
    int wv = (blockIdx.x * 256 + threadIdx.x) >> 6;
    int lane = threadIdx.x & 63;
    int grp = lane >> 5, l = lane & 31;
    int node = wv * 2 + grp;
    if (node >= N) return;
    int s0 = offs[node], s1 = offs[node + 1];
    float ax = 0.f, ay = 0.f, az = 0.f, aw = 0.f;
    int k = s0;
    for (; k + 4 <= s1; k += 4) {
        int i0 = srcs[k], i1 = srcs[k + 1], i2 = srcs[k + 2], i3 = srcs[k + 3];
        float4 a = *(const float4*)(X + (size_t)i0 * 128 + l * 4);
        float4 b = *(const float4*)(X + (size_t)i1 * 128 + l * 4);
        float4 c = *(const float4*)(X + (size_t)i2 * 128 + l * 4);
        float4 d = *(const float4*)(X + (size_t)i3 * 128 + l * 4);
        ax += (a.x + b.x) + (c.x + d.x);
        ay += (a.y + b.y) + (c.y + d.y);
        az += (a.z + b.z) + (c.z + d.z);
        aw += (a.w + b.w) + (c.w + d.w);
    }
    for (; k < s1; ++k) {
        int s = srcs[k];
        float4 a = *(const float4*)(X + (size_t)s * 128 + l * 4);
        ax += a.x; ay += a.y; az += a.z; aw += a.w;
    }
    int c = s1 - s0;
    float sc = 1.0f / (float)(c > 1 ? c : 1);
    float4 r; r.x = ax * sc; r.y = ay * sc; r.z = az * sc; r.w = aw * sc;
    *(float4*)(outm + (size_t)node * 128 + l * 4) = r;
}

// 4 nodes per wave: 16 lanes x float4 = 256B = one 64-ch Y2 row.
__global__ __launch_bounds__(256) void agg_add_out(
    const float* __restrict__ Y2Z, const int* __restrict__ offs,
    const int* __restrict__ srcs, float* __restrict__ out, int N) {
    int wv = (blockIdx.x * 256 + threadIdx.x) >> 6;
    int lane = threadIdx.x & 63;
    int grp = lane >> 4, l = lane & 15;
    int node = wv * 4 + grp;
    if (node >= N) return;
    int s0 = offs[node], s1 = offs[node + 1];
    // Z (self) term early so it overlaps the gather loop
    float4 z = *(const float4*)(Y2Z + (size_t)node * 128 + 64 + l * 4);
    float ax = 0.f, ay = 0.f, az = 0.f, aw = 0.f;
    int k = s0;
    for (; k + 4 <= s1; k += 4) {
        int i0 = srcs[k], i1 = srcs[k + 1], i2 = srcs[k + 2], i3 = srcs[k + 3];
        float4 a = *(const float4*)(Y2Z + (size_t)i0 * 128 + l * 4);
        float4 b = *(const float4*)(Y2Z + (size_t)i1 * 128 + l * 4);
        float4 c = *(const float4*)(Y2Z + (size_t)i2 * 128 + l * 4);
        float4 d = *(const float4*)(Y2Z + (size_t)i3 * 128 + l * 4);
        ax += (a.x + b.x) + (c.x + d.x);
        ay += (a.y + b.y) + (c.y + d.y);
        az += (a.z + b.z) + (c.z + d.z);
        aw += (a.w + b.w) + (c.w + d.w);
    }
    for (; k < s1; ++k) {
        int s = srcs[k];
        float4 a = *(const float4*)(Y2Z + (size_t)s * 128 + l * 4);
        ax += a.x; ay += a.y; az += a.z; aw += a.w;
    }
    int c = s1 - s0;
    float sc = 1.0f / (float)(c > 1 ? c : 1);
    float4 r;
    r.x = ax * sc + z.x; r.y = ay * sc + z.y;
    r.z = az * sc + z.z; r.w = aw * sc + z.w;
    *(float4*)(out + (size_t)node * 64 + l * 4) = r;
}

// ---------------- split-bf16 MFMA GEMM ----------------
// C[M][NT] = (A' @ Wcat^T) + bias, A'[r][k] = (k<Ksplit ? A1[r][k] : A2[r][k-Ksplit])
// Wcat given pre-split as Whi/Wlo [NT][K] bf16. Tile 128x128, BK=32, 4 waves (2x2), 64x64/wave.
// LDS rows of 32 bf16 (64B), XOR swizzle: byte_off ^= ((row>>1)&3)<<4.
//   Bank-group (addr bits 4..6) = {r&1, lg ^ ((r>>1)&3)} -> all 8 groups hit across 16
//   consecutive rows => 2-way (free) ds_read_b128.

template<bool RELU>
__global__ __launch_bounds__(256) void gemm_split(
    const float* __restrict__ A1, int lda1,
    const float* __restrict__ A2, int lda2, int Ksplit,
    const __bf16* __restrict__ Whi, const __bf16* __restrict__ Wlo,
    const float* __restrict__ bias, float* __restrict__ C,
    int M, int K, int NT) {
    __shared__ __bf16 Ah[128 * 32], Al[128 * 32], Bh[128 * 32], Bl[128 * 32];
    const int tid = threadIdx.x;
    const int lane = tid & 63;
    const int wid = tid >> 6;
    const int wm = wid >> 1, wn = wid & 1;
    const int l15 = lane & 15, lg = lane >> 4;
    const long row0 = (long)blockIdx.x * 128;
    const int col0 = blockIdx.y * 128;

    const int ar  = tid >> 3;            // A-stage row 0..31 (+p*32)
    const int acx = (tid & 7) * 4;       // A-stage float col
    const int wrr = tid >> 2;            // W-stage row 0..63 (+p*64)
    const int wcx = (tid & 3) * 8;       // W-stage bf16 col

    f32x4 acc[4][4] = {};

    for (int k0 = 0; k0 < K; k0 += 32) {
        const float* Asrc; int lda, kk0;
        if (k0 < Ksplit) { Asrc = A1; lda = lda1; kk0 = k0; }
        else             { Asrc = A2; lda = lda2; kk0 = k0 - Ksplit; }

        // stage A: 128x32 fp32 -> hi/lo bf16 in LDS (swizzled)
        #pragma unroll
        for (int p = 0; p < 4; ++p) {
            int r = ar + p * 32;
            long gr = row0 + r;
            float4 v = make_float4(0.f, 0.f, 0.f, 0.f);
            if (gr < M) v = *(const float4*)(Asrc + gr * (long)lda + kk0 + acx);
            __bf16 h0 = (__bf16)v.x, h1 = (__bf16)v.y, h2 = (__bf16)v.z, h3 = (__bf16)v.w;
            bf16x4 hv, lv;
            hv[0] = h0; hv[1] = h1; hv[2] = h2; hv[3] = h3;
            lv[0] = (__bf16)(v.x - (float)h0); lv[1] = (__bf16)(v.y - (float)h1);
            lv[2] = (__bf16)(v.z - (float)h2); lv[3] = (__bf16)(v.w - (float)h3);
            int off = (r * 64 + acx * 2) ^ (((r >> 1) & 3) << 4);
            *(bf16x4*)((char*)Ah + off) = hv;
            *(bf16x4*)((char*)Al + off) = lv;
        }
        // stage W: 128x32 bf16 hi/lo (pre-split in global) -> LDS (swizzled)
        #pragma unroll
        for (int p = 0; p < 2; ++p) {
            int n = wrr + p * 64;
            long wrow = (long)(col0 + n) * K + k0 + wcx;
            bf16x8 hv = *(const bf16x8*)(Whi + wrow);
            bf16x8 lv = *(const bf16x8*)(Wlo + wrow);
            int off = (n * 64 + wcx * 2) ^ (((n >> 1) & 3) << 4);
            *(bf16x8*)((char*)Bh + off) = hv;
            *(bf16x8*)((char*)Bl + off) = lv;
        }
        __syncthreads();

        bf16x8 ah[4], al[4], bh[4], bl[4];
        #pragma unroll
        for (int m = 0; m < 4; ++m) {
            int r = wm * 64 + m * 16 + l15;
            int off = (r * 64 + lg * 16) ^ (((r >> 1) & 3) << 4);
            ah[m] = *(const bf16x8*)((char*)Ah + off);
            al[m] = *(const bf16x8*)((char*)Al + off);
        }
        #pragma unroll
        for (int n = 0; n < 4; ++n) {
            int r = wn * 64 + n * 16 + l15;
            int off = (r * 64 + lg * 16) ^ (((r >> 1) & 3) << 4);
            bh[n] = *(const bf16x8*)((char*)Bh + off);
            bl[n] = *(const bf16x8*)((char*)Bl + off);
        }
        #pragma unroll
        for (int m = 0; m < 4; ++m)
            #pragma unroll
            for (int n = 0; n < 4; ++n) {
                acc[m][n] = __builtin_amdgcn_mfma_f32_16x16x32_bf16(ah[m], bh[n], acc[m][n], 0, 0, 0);
                acc[m][n] = __builtin_amdgcn_mfma_f32_16x16x32_bf16(ah[m], bl[n], acc[m][n], 0, 0, 0);
                acc[m][n] = __builtin_amdgcn_mfma_f32_16x16x32_bf16(al[m], bh[n], acc[m][n], 0, 0, 0);
            }
        __syncthreads();
    }

    // epilogue: C/D layout col=lane&15, row=(lane>>4)*4+reg  [m89]
    float bvals[4];
    #pragma unroll
    for (int n = 0; n < 4; ++n) bvals[n] = bias[col0 + wn * 64 + n * 16 + l15];
    #pragma unroll
    for (int m = 0; m < 4; ++m) {
        long gr0 = row0 + wm * 64 + m * 16 + lg * 4;
        #pragma unroll
        for (int rr = 0; rr < 4; ++rr) {
            long gr = gr0 + rr;
            if (gr < M) {
                #pragma unroll
                for (int n = 0; n < 4; ++n) {
                    int gc = col0 + wn * 64 + n * 16 + l15;
                    float v = acc[m][n][rr] + bvals[n];
                    if (RELU) v = fmaxf(v, 0.f);
                    C[gr * NT + gc] = v;
                }
            }
        }
    }
}

// ---------------- launch ----------------

extern "C" void kernel_launch(void* const* d_in, const int* in_sizes, int n_in,
                              void* d_out, int out_size, void* d_ws, size_t ws_size,
                              hipStream_t stream) {
    const float* x   = (const float*)d_in[0];
    const int*   ei  = (const int*)d_in[1];
    const float* W1l = (const float*)d_in[2];
    const float* b1  = (const float*)d_in[3];
    const float* W1r = (const float*)d_in[4];
    const float* W2l = (const float*)d_in[5];
    const float* b2  = (const float*)d_in[6];
    const float* W2r = (const float*)d_in[7];
    float* out = (float*)d_out;

    const int N = in_sizes[0] / IN_CH;      // 100000
    const int E = in_sizes[1] / 2;          // 640000
    const int* src = ei;
    const int* dst = ei + E;

    // ws carve: h[N*256] | buf[N*128] | CSR ints | bf16 weight splits | bias2
    float* h   = (float*)d_ws;
    float* buf = h + (size_t)N * HID_CH;
    int* deg  = (int*)(buf + (size_t)N * 128);
    int* offs = deg + N;
    int* cur  = offs + (N + 8);
    int* bsum = cur + N;
    int* srcs = bsum + 512;
    uintptr_t pp = (uintptr_t)(srcs + E);
    pp = (pp + 15) & ~(uintptr_t)15;
    __bf16* W1h  = (__bf16*)pp;             // [256][256]
    __bf16* W1lo = W1h + 256 * 256;
    __bf16* W2h  = W1lo + 256 * 256;        // [128][256]
    __bf16* W2lo = W2h + 128 * 256;
    float* bias2 = (float*)(W2lo + 128 * 256);

    hipMemsetAsync(deg, 0, sizeof(int) * N, stream);
    hipMemsetAsync(cur, 0, sizeof(int) * N, stream);

    convert_weights<<<256, 256, 0, stream>>>(W1l, W1r, W2l, W2r, b2,
                                             W1h, W1lo, W2h, W2lo, bias2);

    hist_kernel<<<1024, 256, 0, stream>>>(dst, deg, E);
    int nb = (N + 511) / 512;
    scan_block<<<nb, 512, 0, stream>>>(deg, offs, bsum, N);
    scan_sums<<<1, 256, 0, stream>>>(bsum, nb);
    scan_add<<<(N + 255) / 256, 256, 0, stream>>>(offs, bsum, N, E);
    fill_csr<<<1024, 256, 0, stream>>>(src, dst, offs, cur, srcs, E);

    // layer 1: aggregate-first, then h = relu([mean1|x] @ [W1l|W1r]^T + b1)
    agg_mean128<<<((N + 1) / 2 * 64 + 255) / 256, 256, 0, stream>>>(x, offs, srcs, buf, N);
    dim3 g1((N + 127) / 128, 2);
    gemm_split<true><<<g1, 256, 0, stream>>>(buf, IN_CH, x, IN_CH, IN_CH,
                                             W1h, W1lo, b1, h, N, 2 * IN_CH, HID_CH);

    // layer 2: transform-first Y2Z = h @ [W2l;W2r]^T (+bias2 masked), then 64-dim aggregate
    dim3 g2((N + 127) / 128, 1);
    gemm_split<false><<<g2, 256, 0, stream>>>(nullptr, 0, h, HID_CH, 0,
                                              W2h, W2lo, bias2, buf, N, HID_CH, 2 * OUT_CH);
    agg_add_out<<<((N + 3) / 4 * 64 + 255) / 256, 256, 0, stream>>>(buf, offs, srcs, out, N);
}

// Round 6
// 371.256 us; speedup vs baseline: 1.6617x; 1.0145x over previous
//
#include <hip/hip_runtime.h>

// GraphSAGE 2-layer, fp32 in/out, MI355X.
//   CSR build -> mean1 = agg(x)/cnt
//   fused: H = relu([mean1|x]@[W1l|W1r]^T + b1) (regs) -> LDS hi/lo -> Y2Z = H@[W2l;W2r]^T (+b2 on Z)
//   out = agg(Y2)/cnt + Z
// Split-bf16: v = hi + lo; A@B ~= Ahi@Bhi + Ahi@Blo + Alo@Bhi (fp32 acc, ~2^-16 rel err)
// R4/R5: fused L1+L2 GEMM — kills the h round-trip (204 MB of HBM traffic) + one launch.
//     (R4 profile: gemm1 83.5us stall-bound, MfmaUtil 19%, HBM 31%, occupancy ~2 blocks/CU.)
//     R5: broker timeout, kernel never ran; re-audited (aliasing, swizzle involution,
//     bank groups, LDS cap, epilogue coverage) — no change, resubmitted.

#define IN_CH  128
#define HID_CH 256
#define OUT_CH 64

typedef __bf16 bf16x8 __attribute__((ext_vector_type(8)));
typedef __bf16 bf16x4 __attribute__((ext_vector_type(4)));
typedef float  f32x4  __attribute__((ext_vector_type(4)));

// ---------------- CSR build ----------------

__global__ void hist_kernel(const int* __restrict__ dst, int* __restrict__ deg, int E) {
    for (int e = blockIdx.x * blockDim.x + threadIdx.x; e < E; e += gridDim.x * blockDim.x)
        atomicAdd(&deg[dst[e]], 1);
}

__global__ void scan_block(const int* __restrict__ deg, int* __restrict__ offs,
                           int* __restrict__ bsum, int n) {
    __shared__ int s[512];
    int i = blockIdx.x * 512 + threadIdx.x;
    int v = (i < n) ? deg[i] : 0;
    s[threadIdx.x] = v;
    __syncthreads();
    #pragma unroll
    for (int d = 1; d < 512; d <<= 1) {
        int t = (threadIdx.x >= d) ? s[threadIdx.x - d] : 0;
        __syncthreads();
        s[threadIdx.x] += t;
        __syncthreads();
    }
    if (i < n) offs[i] = s[threadIdx.x] - v;
    if (threadIdx.x == 511) bsum[blockIdx.x] = s[511];
}

__global__ void scan_sums(int* __restrict__ bsum, int nb) {
    __shared__ int s[256];
    int v = (threadIdx.x < nb) ? bsum[threadIdx.x] : 0;
    s[threadIdx.x] = v;
    __syncthreads();
    #pragma unroll
    for (int d = 1; d < 256; d <<= 1) {
        int t = (threadIdx.x >= d) ? s[threadIdx.x - d] : 0;
        __syncthreads();
        s[threadIdx.x] += t;
        __syncthreads();
    }
    if (threadIdx.x < nb) bsum[threadIdx.x] = s[threadIdx.x] - v;
}

__global__ void scan_add(int* __restrict__ offs, const int* __restrict__ bsum, int n, int E) {
    int i = blockIdx.x * blockDim.x + threadIdx.x;
    if (i < n) offs[i] += bsum[i >> 9];
    if (i == 0) offs[n] = E;
}

__global__ void fill_csr(const int* __restrict__ src, const int* __restrict__ dst,
                         const int* __restrict__ offs, int* __restrict__ cur,
                         int* __restrict__ srcs, int E) {
    for (int e = blockIdx.x * blockDim.x + threadIdx.x; e < E; e += gridDim.x * blockDim.x) {
        int d = dst[e];
        int p = atomicAdd(&cur[d], 1);
        srcs[offs[d] + p] = src[e];
    }
}

// ---------------- weight split (fp32 -> bf16 hi/lo), once per launch ----------------

__global__ void convert_weights(const float* __restrict__ W1l, const float* __restrict__ W1r,
                                const float* __restrict__ W2l, const float* __restrict__ W2r,
                                const float* __restrict__ b2,
                                __bf16* __restrict__ W1h, __bf16* __restrict__ W1lo,
                                __bf16* __restrict__ W2h, __bf16* __restrict__ W2lo,
                                float* __restrict__ bias2) {
    int i = blockIdx.x * 256 + threadIdx.x;
    if (i < 256 * 256) {                 // W1cat [256][256]: k<128 from W1l, else W1r
        int n = i >> 8, k = i & 255;
        float v = (k < 128) ? W1l[n * 128 + k] : W1r[n * 128 + (k - 128)];
        __bf16 h = (__bf16)v;
        W1h[i] = h; W1lo[i] = (__bf16)(v - (float)h);
    }
    if (i < 128 * 256) {                 // W2cat [128][256]: n<64 from W2l (Y2), else W2r (Z)
        int n = i >> 8, k = i & 255;
        float v = (n < 64) ? W2l[n * 256 + k] : W2r[(n - 64) * 256 + k];
        __bf16 h = (__bf16)v;
        W2h[i] = h; W2lo[i] = (__bf16)(v - (float)h);
    }
    if (i < 128) bias2[i] = (i < 64) ? 0.f : b2[i - 64];
}

// ---------------- aggregation (multi-node waves, 4x unrolled gathers) ----------------

// 2 nodes per wave: 32 lanes x float4 = 512B = one 128-ch fp32 row.
__global__ __launch_bounds__(256) void agg_mean128(
    const float* __restrict__ X, const int* __restrict__ offs,
    const int* __restrict__ srcs, float* __restrict__ outm, int N) {
    int wv = (blockIdx.x * 256 + threadIdx.x) >> 6;
    int lane = threadIdx.x & 63;
    int grp = lane >> 5, l = lane & 31;
    int node = wv * 2 + grp;
    if (node >= N) return;
    int s0 = offs[node], s1 = offs[node + 1];
    float ax = 0.f, ay = 0.f, az = 0.f, aw = 0.f;
    int k = s0;
    for (; k + 4 <= s1; k += 4) {
        int i0 = srcs[k], i1 = srcs[k + 1], i2 = srcs[k + 2], i3 = srcs[k + 3];
        float4 a = *(const float4*)(X + (size_t)i0 * 128 + l * 4);
        float4 b = *(const float4*)(X + (size_t)i1 * 128 + l * 4);
        float4 c = *(const float4*)(X + (size_t)i2 * 128 + l * 4);
        float4 d = *(const float4*)(X + (size_t)i3 * 128 + l * 4);
        ax += (a.x + b.x) + (c.x + d.x);
        ay += (a.y + b.y) + (c.y + d.y);
        az += (a.z + b.z) + (c.z + d.z);
        aw += (a.w + b.w) + (c.w + d.w);
    }
    for (; k < s1; ++k) {
        int s = srcs[k];
        float4 a = *(const float4*)(X + (size_t)s * 128 + l * 4);
        ax += a.x; ay += a.y; az += a.z; aw += a.w;
    }
    int c = s1 - s0;
    float sc = 1.0f / (float)(c > 1 ? c : 1);
    float4 r; r.x = ax * sc; r.y = ay * sc; r.z = az * sc; r.w = aw * sc;
    *(float4*)(outm + (size_t)node * 128 + l * 4) = r;
}

// 4 nodes per wave: 16 lanes x float4 = 256B = one 64-ch Y2 row.
__global__ __launch_bounds__(256) void agg_add_out(
    const float* __restrict__ Y2Z, const int* __restrict__ offs,
    const int* __restrict__ srcs, float* __restrict__ out, int N) {
    int wv = (blockIdx.x * 256 + threadIdx.x) >> 6;
    int lane = threadIdx.x & 63;
    int grp = lane >> 4, l = lane & 15;
    int node = wv * 4 + grp;
    if (node >= N) return;
    int s0 = offs[node], s1 = offs[node + 1];
    float4 z = *(const float4*)(Y2Z + (size_t)node * 128 + 64 + l * 4);
    float ax = 0.f, ay = 0.f, az = 0.f, aw = 0.f;
    int k = s0;
    for (; k + 4 <= s1; k += 4) {
        int i0 = srcs[k], i1 = srcs[k + 1], i2 = srcs[k + 2], i3 = srcs[k + 3];
        float4 a = *(const float4*)(Y2Z + (size_t)i0 * 128 + l * 4);
        float4 b = *(const float4*)(Y2Z + (size_t)i1 * 128 + l * 4);
        float4 c = *(const float4*)(Y2Z + (size_t)i2 * 128 + l * 4);
        float4 d = *(const float4*)(Y2Z + (size_t)i3 * 128 + l * 4);
        ax += (a.x + b.x) + (c.x + d.x);
        ay += (a.y + b.y) + (c.y + d.y);
        az += (a.z + b.z) + (c.z + d.z);
        aw += (a.w + b.w) + (c.w + d.w);
    }
    for (; k < s1; ++k) {
        int s = srcs[k];
        float4 a = *(const float4*)(Y2Z + (size_t)s * 128 + l * 4);
        ax += a.x; ay += a.y; az += a.z; aw += a.w;
    }
    int c = s1 - s0;
    float sc = 1.0f / (float)(c > 1 ? c : 1);
    float4 r;
    r.x = ax * sc + z.x; r.y = ay * sc + z.y;
    r.z = az * sc + z.z; r.w = aw * sc + z.w;
    *(float4*)(out + (size_t)node * 64 + l * 4) = r;
}

// ---------------- fused L1+L2 GEMM ----------------
// Per block: 64 nodes. 256 threads = 4 waves.
// Phase A: acc[64x256] = split-bf16([mean1|x] @ W1cat^T); wave w -> cols w*64..w*64+63.
// Phase B: H = relu(acc + b1) split to hi/lo bf16 in LDS [64][256], swizzle ^((row&7)<<4) on 512B rows.
// Phase C: Y2Z[64][128] = split-bf16(H @ W2cat^T) + bias2; wave w -> cols w*32..w*32+31.
// LDS 80KB total (2 blocks/CU): H hi 0..32K | H lo 32..64K | W2 stage 64..80K;
// phase-A staging (A 8K + W1 32K = 40K) aliased into 0..40K, dead before H written.

__global__ __launch_bounds__(256) void fused_l1l2(
    const float* __restrict__ mean1, const float* __restrict__ x,
    const __bf16* __restrict__ W1h, const __bf16* __restrict__ W1lo,
    const float* __restrict__ b1,
    const __bf16* __restrict__ W2h, const __bf16* __restrict__ W2lo,
    const float* __restrict__ bias2,
    float* __restrict__ Y2Z, int N) {
    __shared__ __align__(16) char lds[80 * 1024];
    __bf16* Hh    = (__bf16*)lds;                  // [64][256] 32K (phase B/C)
    __bf16* Hl    = (__bf16*)(lds + 32 * 1024);    // 32K
    __bf16* W2hs  = (__bf16*)(lds + 64 * 1024);    // [128][32] 8K
    __bf16* W2ls  = (__bf16*)(lds + 72 * 1024);    // 8K
    __bf16* Ah    = (__bf16*)lds;                  // [64][32] 4K   (phase A only)
    __bf16* Al    = (__bf16*)(lds + 4 * 1024);     // 4K
    __bf16* B1h   = (__bf16*)(lds + 8 * 1024);     // [256][32] 16K
    __bf16* B1l   = (__bf16*)(lds + 24 * 1024);    // 16K

    const int tid = threadIdx.x;
    const int lane = tid & 63;
    const int w = tid >> 6;                        // wave 0..3
    const int l15 = lane & 15, lg = lane >> 4;
    const long row0 = (long)blockIdx.x * 64;

    // ---- phase A: acc = [mean1|x] @ W1cat^T (3-product split) ----
    f32x4 acc[4][4] = {};
    for (int k0 = 0; k0 < 256; k0 += 32) {
        const float* Asrc = (k0 < 128) ? mean1 : x;
        const int kk0 = (k0 < 128) ? k0 : k0 - 128;
        // stage A 64x32 fp32 -> hi/lo: thread -> r=tid>>3 (+p*32), float4 chunk tid&7
        #pragma unroll
        for (int p = 0; p < 2; ++p) {
            int r = (tid >> 3) + p * 32;
            long gr = row0 + r;
            float4 v = make_float4(0.f, 0.f, 0.f, 0.f);
            if (gr < N) v = *(const float4*)(Asrc + gr * 128 + kk0 + (tid & 7) * 4);
            __bf16 h0 = (__bf16)v.x, h1 = (__bf16)v.y, h2 = (__bf16)v.z, h3 = (__bf16)v.w;
            bf16x4 hv, lv;
            hv[0] = h0; hv[1] = h1; hv[2] = h2; hv[3] = h3;
            lv[0] = (__bf16)(v.x - (float)h0); lv[1] = (__bf16)(v.y - (float)h1);
            lv[2] = (__bf16)(v.z - (float)h2); lv[3] = (__bf16)(v.w - (float)h3);
            int off = (r * 64 + (tid & 7) * 8) ^ (((r >> 1) & 3) << 4);
            *(bf16x4*)((char*)Ah + off) = hv;
            *(bf16x4*)((char*)Al + off) = lv;
        }
        // stage W1 256x32 (pre-split): thread -> row=tid>>2 (+p*64), chunk tid&3
        #pragma unroll
        for (int p = 0; p < 4; ++p) {
            int n = (tid >> 2) + p * 64;
            long g = (long)n * 256 + k0 + (tid & 3) * 8;
            bf16x8 hv = *(const bf16x8*)(W1h + g);
            bf16x8 lv = *(const bf16x8*)(W1lo + g);
            int off = (n * 64 + (tid & 3) * 16) ^ (((n >> 1) & 3) << 4);
            *(bf16x8*)((char*)B1h + off) = hv;
            *(bf16x8*)((char*)B1l + off) = lv;
        }
        __syncthreads();
        bf16x8 ah[4], al[4], bh[4], bl[4];
        #pragma unroll
        for (int m = 0; m < 4; ++m) {
            int r = m * 16 + l15;
            int off = (r * 64 + lg * 16) ^ (((r >> 1) & 3) << 4);
            ah[m] = *(const bf16x8*)((char*)Ah + off);
            al[m] = *(const bf16x8*)((char*)Al + off);
        }
        #pragma unroll
        for (int n = 0; n < 4; ++n) {
            int rb = w * 64 + n * 16 + l15;
            int off = (rb * 64 + lg * 16) ^ (((rb >> 1) & 3) << 4);
            bh[n] = *(const bf16x8*)((char*)B1h + off);
            bl[n] = *(const bf16x8*)((char*)B1l + off);
        }
        #pragma unroll
        for (int m = 0; m < 4; ++m)
            #pragma unroll
            for (int n = 0; n < 4; ++n) {
                acc[m][n] = __builtin_amdgcn_mfma_f32_16x16x32_bf16(ah[m], bh[n], acc[m][n], 0, 0, 0);
                acc[m][n] = __builtin_amdgcn_mfma_f32_16x16x32_bf16(ah[m], bl[n], acc[m][n], 0, 0, 0);
                acc[m][n] = __builtin_amdgcn_mfma_f32_16x16x32_bf16(al[m], bh[n], acc[m][n], 0, 0, 0);
            }
        __syncthreads();
    }

    // ---- phase B: H = relu(acc + b1) -> hi/lo LDS (overwrites phase-A staging; all waves synced) ----
    #pragma unroll
    for (int n = 0; n < 4; ++n) {
        int col = w * 64 + n * 16 + l15;
        float bv = b1[col];
        #pragma unroll
        for (int m = 0; m < 4; ++m) {
            #pragma unroll
            for (int rr = 0; rr < 4; ++rr) {
                int row = m * 16 + lg * 4 + rr;
                float v = fmaxf(acc[m][n][rr] + bv, 0.f);
                __bf16 hv = (__bf16)v;
                __bf16 lv = (__bf16)(v - (float)hv);
                int off = (row * 512 + col * 2) ^ ((row & 7) << 4);
                *(__bf16*)((char*)Hh + off) = hv;
                *(__bf16*)((char*)Hl + off) = lv;
            }
        }
    }
    __syncthreads();

    // ---- phase C: Y2Z = H @ W2cat^T + bias2 ----
    f32x4 acc2[4][2] = {};
    for (int k0 = 0; k0 < 256; k0 += 32) {
        // stage W2 128x32: thread -> row=tid>>2 (+p*64), chunk tid&3
        #pragma unroll
        for (int p = 0; p < 2; ++p) {
            int n = (tid >> 2) + p * 64;
            long g = (long)n * 256 + k0 + (tid & 3) * 8;
            bf16x8 hv = *(const bf16x8*)(W2h + g);
            bf16x8 lv = *(const bf16x8*)(W2lo + g);
            int off = (n * 64 + (tid & 3) * 16) ^ (((n >> 1) & 3) << 4);
            *(bf16x8*)((char*)W2hs + off) = hv;
            *(bf16x8*)((char*)W2ls + off) = lv;
        }
        __syncthreads();
        bf16x8 a2h[4], a2l[4], b2h[2], b2l[2];
        #pragma unroll
        for (int m = 0; m < 4; ++m) {
            int row = m * 16 + l15;
            int off = (row * 512 + k0 * 2 + lg * 16) ^ ((row & 7) << 4);
            a2h[m] = *(const bf16x8*)((char*)Hh + off);
            a2l[m] = *(const bf16x8*)((char*)Hl + off);
        }
        #pragma unroll
        for (int n = 0; n < 2; ++n) {
            int rb = w * 32 + n * 16 + l15;
            int off = (rb * 64 + lg * 16) ^ (((rb >> 1) & 3) << 4);
            b2h[n] = *(const bf16x8*)((char*)W2hs + off);
            b2l[n] = *(const bf16x8*)((char*)W2ls + off);
        }
        #pragma unroll
        for (int m = 0; m < 4; ++m)
            #pragma unroll
            for (int n = 0; n < 2; ++n) {
                acc2[m][n] = __builtin_amdgcn_mfma_f32_16x16x32_bf16(a2h[m], b2h[n], acc2[m][n], 0, 0, 0);
                acc2[m][n] = __builtin_amdgcn_mfma_f32_16x16x32_bf16(a2h[m], b2l[n], acc2[m][n], 0, 0, 0);
                acc2[m][n] = __builtin_amdgcn_mfma_f32_16x16x32_bf16(a2l[m], b2h[n], acc2[m][n], 0, 0, 0);
            }
        __syncthreads();
    }

    // ---- epilogue: Y2Z (+bias2: 0 on Y2 half, b2 on Z half) ----
    #pragma unroll
    for (int n = 0; n < 2; ++n) {
        int gc = w * 32 + n * 16 + l15;
        float bv = bias2[gc];
        #pragma unroll
        for (int m = 0; m < 4; ++m) {
            #pragma unroll
            for (int rr = 0; rr < 4; ++rr) {
                long gr = row0 + m * 16 + lg * 4 + rr;
                if (gr < N) Y2Z[gr * 128 + gc] = acc2[m][n][rr] + bv;
            }
        }
    }
}

// ---------------- launch ----------------

extern "C" void kernel_launch(void* const* d_in, const int* in_sizes, int n_in,
                              void* d_out, int out_size, void* d_ws, size_t ws_size,
                              hipStream_t stream) {
    const float* x   = (const float*)d_in[0];
    const int*   ei  = (const int*)d_in[1];
    const float* W1l = (const float*)d_in[2];
    const float* b1  = (const float*)d_in[3];
    const float* W1r = (const float*)d_in[4];
    const float* W2l = (const float*)d_in[5];
    const float* b2  = (const float*)d_in[6];
    const float* W2r = (const float*)d_in[7];
    float* out = (float*)d_out;

    const int N = in_sizes[0] / IN_CH;      // 100000
    const int E = in_sizes[1] / 2;          // 640000
    const int* src = ei;
    const int* dst = ei + E;

    // ws carve: buf1=mean1[N*128] | buf2=Y2Z[N*128] | CSR ints | bf16 weight splits | bias2
    float* buf1 = (float*)d_ws;
    float* buf2 = buf1 + (size_t)N * 128;
    int* deg  = (int*)(buf2 + (size_t)N * 128);
    int* offs = deg + N;
    int* cur  = offs + (N + 8);
    int* bsum = cur + N;
    int* srcs = bsum + 512;
    uintptr_t pp = (uintptr_t)(srcs + E);
    pp = (pp + 15) & ~(uintptr_t)15;
    __bf16* W1h  = (__bf16*)pp;             // [256][256]
    __bf16* W1lo = W1h + 256 * 256;
    __bf16* W2h  = W1lo + 256 * 256;        // [128][256]
    __bf16* W2lo = W2h + 128 * 256;
    float* bias2 = (float*)(W2lo + 128 * 256);

    hipMemsetAsync(deg, 0, sizeof(int) * N, stream);
    hipMemsetAsync(cur, 0, sizeof(int) * N, stream);

    convert_weights<<<256, 256, 0, stream>>>(W1l, W1r, W2l, W2r, b2,
                                             W1h, W1lo, W2h, W2lo, bias2);

    hist_kernel<<<1024, 256, 0, stream>>>(dst, deg, E);
    int nb = (N + 511) / 512;
    scan_block<<<nb, 512, 0, stream>>>(deg, offs, bsum, N);
    scan_sums<<<1, 256, 0, stream>>>(bsum, nb);
    scan_add<<<(N + 255) / 256, 256, 0, stream>>>(offs, bsum, N, E);
    fill_csr<<<1024, 256, 0, stream>>>(src, dst, offs, cur, srcs, E);

    agg_mean128<<<((N + 1) / 2 * 64 + 255) / 256, 256, 0, stream>>>(x, offs, srcs, buf1, N);

    fused_l1l2<<<(N + 63) / 64, 256, 0, stream>>>(buf1, x, W1h, W1lo, b1,
                                                  W2h, W2lo, bias2, buf2, N);

    agg_add_out<<<((N + 3) / 4 * 64 + 255) / 256, 256, 0, stream>>>(buf2, offs, srcs, out, N);
}